// Round 1
// baseline (96.952 us; speedup 1.0000x reference)
//
#include <hip/hip_runtime.h>

// Problem constants (reference: B=8, H=512, W=512, C=32, P=16)
#define NPIX (8 * 512 * 512)          // number of output pixels (b,h,w)
#define FILT_ELEMS (512 * 512 * 8)    // == NPIX, filtered output size

// 8 lanes per pixel; lane j handles channels [4j, 4j+4).
// x: [B,H,W,C] f32 contiguous. w: [16,16,32]. b: [16,16].
// out_f: [B,H,W] (sum over C + bias). out_w: [B,H,W,C] (x * filter).
__global__ __launch_bounds__(256) void linfilter_kernel(
    const float* __restrict__ x,
    const float* __restrict__ w,
    const float* __restrict__ b,
    float* __restrict__ out_f,
    float* __restrict__ out_w)
{
    const int t = blockIdx.x * blockDim.x + threadIdx.x;  // [0, NPIX*8)
    const int j = t & 7;        // quarter-of-C index within pixel
    const int pixel = t >> 3;   // [0, NPIX)

    // pixel = ((bidx*512) + h)*512 + wc ; 512*512 = 2^18
    const int hw = pixel & ((1 << 18) - 1);
    const int h  = hw >> 9;
    const int wc = hw & 511;

    // filter/bias index within the 16x16 tile
    const int wi = ((h & 15) << 4) | (wc & 15);

    // load the weight float4 for this channel quad
    float4 w4 = *reinterpret_cast<const float4*>(w + wi * 32 + j * 4);
    // relu applies ONLY to the absolute top-left 16x16 tile of the image
    if ((h < 16) && (wc < 16)) {
        w4.x = fmaxf(w4.x, 0.0f);
        w4.y = fmaxf(w4.y, 0.0f);
        w4.z = fmaxf(w4.z, 0.0f);
        w4.w = fmaxf(w4.w, 0.0f);
    }

    const int xoff = pixel * 32 + j * 4;  // < 2^27, fits int
    const float4 x4 = *reinterpret_cast<const float4*>(x + xoff);

    float4 o4;
    o4.x = x4.x * w4.x;
    o4.y = x4.y * w4.y;
    o4.z = x4.z * w4.z;
    o4.w = x4.w * w4.w;

    *reinterpret_cast<float4*>(out_w + xoff) = o4;

    // sum over this quad, then across the 8 lanes of the group
    float s = (o4.x + o4.y) + (o4.z + o4.w);
    s += __shfl_xor(s, 1, 8);
    s += __shfl_xor(s, 2, 8);
    s += __shfl_xor(s, 4, 8);

    if (j == 0) {
        out_f[pixel] = s + b[wi];
    }
}

extern "C" void kernel_launch(void* const* d_in, const int* in_sizes, int n_in,
                              void* d_out, int out_size, void* d_ws, size_t ws_size,
                              hipStream_t stream) {
    const float* x = (const float*)d_in[0];   // [8,512,512,32]
    const float* w = (const float*)d_in[1];   // [1,16,16,32]
    const float* b = (const float*)d_in[2];   // [1,16,16,1]

    float* out_f = (float*)d_out;                 // first output: [8,512,512,1]
    float* out_w = (float*)d_out + FILT_ELEMS;    // second output: [8,512,512,32]

    const int total_threads = NPIX * 8;           // 16,777,216
    const int block = 256;
    const int grid = total_threads / block;       // 65536

    linfilter_kernel<<<grid, block, 0, stream>>>(x, w, b, out_f, out_w);
}

// Round 3
// 91.495 us; speedup vs baseline: 1.0596x; 1.0596x over previous
//
#include <hip/hip_runtime.h>

// Problem constants (reference: B=8, H=512, W=512, C=32, P=16)
#define NPIX (8 * 512 * 512)          // number of output pixels (b,h,w)
#define FILT_ELEMS (512 * 512 * 8)    // == NPIX, filtered output size

// native clang vector type — accepted by __builtin_nontemporal_load/store
typedef float f32x4 __attribute__((ext_vector_type(4)));

// 8 lanes per pixel; lane j handles channels [4j, 4j+4).
// x: [B,H,W,C] f32 contiguous. w: [16,16,32]. b: [16,16].
// out_f: [B,H,W] (sum over C + bias). out_w: [B,H,W,C] (x * filter).
__global__ __launch_bounds__(256) void linfilter_kernel(
    const float* __restrict__ x,
    const float* __restrict__ w,
    const float* __restrict__ b,
    float* __restrict__ out_f,
    float* __restrict__ out_w)
{
    const int t = blockIdx.x * blockDim.x + threadIdx.x;  // [0, NPIX*8)
    const int j = t & 7;        // quarter-of-C index within pixel
    const int pixel = t >> 3;   // [0, NPIX)

    // pixel = ((bidx*512) + h)*512 + wc ; 512*512 = 2^18
    const int hw = pixel & ((1 << 18) - 1);
    const int h  = hw >> 9;
    const int wc = hw & 511;

    // filter/bias index within the 16x16 tile
    const int wi = ((h & 15) << 4) | (wc & 15);

    // load the weight float4 for this channel quad (small, cache-resident)
    f32x4 w4 = *reinterpret_cast<const f32x4*>(w + wi * 32 + j * 4);
    // relu applies ONLY to the absolute top-left 16x16 tile of the image
    if ((h < 16) && (wc < 16)) {
        w4.x = fmaxf(w4.x, 0.0f);
        w4.y = fmaxf(w4.y, 0.0f);
        w4.z = fmaxf(w4.z, 0.0f);
        w4.w = fmaxf(w4.w, 0.0f);
    }

    const int xoff = pixel * 32 + j * 4;  // < 2^27, fits int

    // streaming (non-temporal) read of x — read once, never reused
    const f32x4 x4 = __builtin_nontemporal_load(
        reinterpret_cast<const f32x4*>(x + xoff));

    f32x4 o4 = x4 * w4;

    // streaming (non-temporal) write of out_w — written once, never re-read
    __builtin_nontemporal_store(o4, reinterpret_cast<f32x4*>(out_w + xoff));

    // sum over this quad, then across the 8 lanes of the group
    float s = (o4.x + o4.y) + (o4.z + o4.w);
    s += __shfl_xor(s, 1, 8);
    s += __shfl_xor(s, 2, 8);
    s += __shfl_xor(s, 4, 8);

    if (j == 0) {
        __builtin_nontemporal_store(s + b[wi], out_f + pixel);
    }
}

extern "C" void kernel_launch(void* const* d_in, const int* in_sizes, int n_in,
                              void* d_out, int out_size, void* d_ws, size_t ws_size,
                              hipStream_t stream) {
    const float* x = (const float*)d_in[0];   // [8,512,512,32]
    const float* w = (const float*)d_in[1];   // [1,16,16,32]
    const float* b = (const float*)d_in[2];   // [1,16,16,1]

    float* out_f = (float*)d_out;                 // first output: [8,512,512,1]
    float* out_w = (float*)d_out + FILT_ELEMS;    // second output: [8,512,512,32]

    const int total_threads = NPIX * 8;           // 16,777,216
    const int block = 256;
    const int grid = total_threads / block;       // 65536

    linfilter_kernel<<<grid, block, 0, stream>>>(x, w, b, out_f, out_w);
}